// Round 9
// baseline (310.471 us; speedup 1.0000x reference)
//
#include <hip/hip_runtime.h>

// B=2, S=4096, D=512, H=8, HD=64. fp32 in/out; bf16 MFMA internally.
// ws (25 MiB): qy[2][4096][8][64] (Q, then Y) | K[16][4096][64] | V^T[16][64][4096]
//              | ml[2][16][4096][2] f32
// d_out (16 MiB) doubles as PO[2][2][4096][8][64] bf16 (dead until gemm3).

typedef __bf16 bf16x8 __attribute__((ext_vector_type(8)));
typedef float f32x4 __attribute__((ext_vector_type(4)));
typedef unsigned short u16;

#define MFMA(a, b, c) __builtin_amdgcn_mfma_f32_16x16x32_bf16(a, b, c, 0, 0, 0)
#define QSCALE 0.18033688011112042f   // 1/sqrt(64) * log2(e)

__device__ __forceinline__ float exp2_fast(float x) {
    return __builtin_amdgcn_exp2f(x);
}
// native bf16 convert (v_cvt hw path, not the 4-op manual RNE sequence)
__device__ __forceinline__ u16 f2bf(float f) {
    union { __bf16 h; u16 u; } v; v.h = (__bf16)f; return v.u;
}
__device__ __forceinline__ ushort4 f4_to_bf4(float4 v) {
    ushort4 r;
    r.x = f2bf(v.x); r.y = f2bf(v.y); r.z = f2bf(v.z); r.w = f2bf(v.w);
    return r;
}
__device__ __forceinline__ void load_lds16(const u16* g, u16* l) {
    __builtin_amdgcn_global_load_lds(
        (const __attribute__((address_space(1))) void*)g,
        (__attribute__((address_space(3))) void*)l, 16, 0, 0);
}

// ---------------------------------------------------------------------------
// GEMM1: qkv = x @ Wqkv^T + b (fp32 in, native-cvt during staging)
// ---------------------------------------------------------------------------
__global__ __launch_bounds__(256) void gemm_qkv_k(
    const float* __restrict__ X, const float* __restrict__ W,
    const float* __restrict__ bias,
    u16* __restrict__ QY, u16* __restrict__ Ko, u16* __restrict__ Vto)
{
    __shared__ u16 As[128 * 32];
    __shared__ u16 Bs[128 * 32];
    const int K = 512;
    const int tid = threadIdx.x, wave = tid >> 6, lane = tid & 63;
    const int l15 = lane & 15, quad = lane >> 4;
    const int bm = blockIdx.x * 128, bn = blockIdx.y * 128;
    const int wr = wave >> 1, wc = wave & 1;
    const int srow = tid >> 1;
    const int sc0 = (tid & 1) * 16;

    f32x4 acc[4][4] = {};
    for (int k0 = 0; k0 < K; k0 += 32) {
        __syncthreads();
#pragma unroll
        for (int j = 0; j < 4; j++) {
            float4 xv = *(const float4*)&X[(bm + srow) * K + k0 + sc0 + j * 4];
            float4 wv = *(const float4*)&W[(bn + srow) * K + k0 + sc0 + j * 4];
            *(ushort4*)&As[srow * 32 + sc0 + j * 4] = f4_to_bf4(xv);
            *(ushort4*)&Bs[srow * 32 + sc0 + j * 4] = f4_to_bf4(wv);
        }
        __syncthreads();
        bf16x8 a[4], b[4];
#pragma unroll
        for (int i = 0; i < 4; i++)
            a[i] = *(const bf16x8*)&As[(wr * 64 + i * 16 + l15) * 32 + quad * 8];
#pragma unroll
        for (int j = 0; j < 4; j++)
            b[j] = *(const bf16x8*)&Bs[(wc * 64 + j * 16 + l15) * 32 + quad * 8];
#pragma unroll
        for (int i = 0; i < 4; i++)
#pragma unroll
            for (int j = 0; j < 4; j++)
                acc[i][j] = MFMA(a[i], b[j], acc[i][j]);
    }

    const int nbase = bn + wc * 64;
    const int which = nbase >> 9;  // 0=q 1=k 2=v
#pragma unroll
    for (int j = 0; j < 4; j++) {
        const int n_g = nbase + j * 16 + l15;
        const float bv = bias[n_g];
        const int d = n_g & 511, h = d >> 6, hd = d & 63;
#pragma unroll
        for (int i = 0; i < 4; i++) {
            const int m0 = bm + wr * 64 + i * 16 + quad * 4;
            const int b_ = m0 >> 12, s0 = m0 & 4095;
            if (which == 2) {
                ushort4 pk;
                pk.x = f2bf(acc[i][j][0] + bv);
                pk.y = f2bf(acc[i][j][1] + bv);
                pk.z = f2bf(acc[i][j][2] + bv);
                pk.w = f2bf(acc[i][j][3] + bv);
                *(ushort4*)&Vto[((b_ * 8 + h) * 64 + hd) * 4096 + s0] = pk;
            } else if (which == 1) {
#pragma unroll
                for (int r = 0; r < 4; r++)
                    Ko[((b_ * 8 + h) * 4096 + s0 + r) * 64 + hd] = f2bf(acc[i][j][r] + bv);
            } else {
#pragma unroll
                for (int r = 0; r < 4; r++)
                    QY[((b_ * 4096 + s0 + r) * 8 + h) * 64 + hd] =
                        f2bf((acc[i][j][r] + bv) * QSCALE);
            }
        }
    }
}

// ---------------------------------------------------------------------------
// Split-K flash attention, causal, S^T + transposed PV. Block = 128 q-rows,
// 4 waves x 32 rows (two 16-row col-groups share every K/V fragment read).
// blockIdx.x in [0,64): qt = 31-(x>>1) (heavy first), seg = x&1; segment
// covers K-tiles [0,qt+1) or [qt+1,2qt+2) => max chain 32 tiles.
// 1024 blocks = exactly 4/CU (36.9 KiB LDS). Reg prefetch, LS=72.
// ---------------------------------------------------------------------------
#define LS 72

__global__ __launch_bounds__(256, 4) void attn_k(
    const u16* __restrict__ QY, const u16* __restrict__ Kk, const u16* __restrict__ Vt,
    u16* __restrict__ PO, float* __restrict__ ML)
{
    __shared__ u16 Ks[64 * LS];        // [key][hd]
    __shared__ u16 Vs[64 * LS];        // [hd][key]
    __shared__ u16 Ps[4 * 32 * LS];    // per-wave P, [qrow(32)][key]

    const int tid = threadIdx.x, wave = tid >> 6, lane = tid & 63;
    const int l15 = lane & 15, quad = lane >> 4;
    const int bh = blockIdx.y;
    const int b_ = bh >> 3, h = bh & 7;
    const int xi = (int)blockIdx.x;
    const int qt = 31 - (xi >> 1);
    const int seg = xi & 1;
    const int total = 2 * qt + 2;
    const int half = qt + 1;
    const int kt0 = seg ? half : 0;
    const int kt1 = seg ? total : half;
    const int base_r = qt * 128 + wave * 32;

    // Q frags (B-operand of S^T = K Q^T): n = qrow = g*16+l15, k = hd
    bf16x8 qf[2][2];
#pragma unroll
    for (int g = 0; g < 2; g++) {
        const u16* qp = &QY[((b_ * 4096 + base_r + g * 16 + l15) * 8 + h) * 64];
        qf[g][0] = *(const bf16x8*)&qp[quad * 8];
        qf[g][1] = *(const bf16x8*)&qp[32 + quad * 8];
    }

    f32x4 o[2][4] = {};                // O^T per group: row = hd, col = qrow
    float m_st[2] = {-1e30f, -1e30f}, l_st[2] = {0.0f, 0.0f};

    const int srow = tid >> 2;
    const int scol = (tid & 3) * 16;
    const u16* Kg = &Kk[(bh * 4096 + srow) * 64 + scol];
    const u16* Vg = &Vt[(bh * 64 + srow) * 4096 + scol];

    bf16x8 pk0 = *(const bf16x8*)&Kg[kt0 * 4096];
    bf16x8 pk1 = *(const bf16x8*)&Kg[kt0 * 4096 + 8];
    bf16x8 pv0 = *(const bf16x8*)&Vg[kt0 * 64];
    bf16x8 pv1 = *(const bf16x8*)&Vg[kt0 * 64 + 8];

    for (int kt = kt0; kt < kt1; kt++) {
        const int k0 = kt * 64;
        __syncthreads();
        *(bf16x8*)&Ks[srow * LS + scol] = pk0;
        *(bf16x8*)&Ks[srow * LS + scol + 8] = pk1;
        *(bf16x8*)&Vs[srow * LS + scol] = pv0;
        *(bf16x8*)&Vs[srow * LS + scol + 8] = pv1;
        if (kt + 1 < kt1) {
            pk0 = *(const bf16x8*)&Kg[(kt + 1) * 4096];
            pk1 = *(const bf16x8*)&Kg[(kt + 1) * 4096 + 8];
            pv0 = *(const bf16x8*)&Vg[(kt + 1) * 64];
            pv1 = *(const bf16x8*)&Vg[(kt + 1) * 64 + 8];
        }
        __syncthreads();

        // ---- S^T = K Q^T: K frags read ONCE, used by both groups ----
        f32x4 sc[2][4];
#pragma unroll
        for (int j = 0; j < 4; j++) {
            const int krow = j * 16 + l15;
            bf16x8 kf0 = *(const bf16x8*)&Ks[krow * LS + quad * 8];
            bf16x8 kf1 = *(const bf16x8*)&Ks[krow * LS + 32 + quad * 8];
#pragma unroll
            for (int g = 0; g < 2; g++) {
                f32x4 s = {};
                s = MFMA(kf0, qf[g][0], s);
                s = MFMA(kf1, qf[g][1], s);
                sc[g][j] = s;
            }
        }
        // ---- online softmax per group (lane owns qrow = base_r+g*16+l15) ----
        bf16x8 pf[2][2];
#pragma unroll
        for (int g = 0; g < 2; g++) {
            const int qrow = base_r + g * 16 + l15;
            const bool needmask = (k0 + 63 > base_r + g * 16);
            float sv[4][4];
#pragma unroll
            for (int j = 0; j < 4; j++)
#pragma unroll
                for (int r = 0; r < 4; r++) {
                    float v = sc[g][j][r];
                    if (needmask) {
                        const int key = k0 + j * 16 + quad * 4 + r;
                        if (key > qrow) v = -1e30f;
                    }
                    sv[j][r] = v;
                }
            float rmax = sv[0][0];
#pragma unroll
            for (int j = 0; j < 4; j++)
#pragma unroll
                for (int r = 0; r < 4; r++) rmax = fmaxf(rmax, sv[j][r]);
            rmax = fmaxf(rmax, __shfl_xor(rmax, 16));
            rmax = fmaxf(rmax, __shfl_xor(rmax, 32));
            const float mnew = fmaxf(m_st[g], rmax);
            const float alpha = exp2_fast(m_st[g] - mnew);
            m_st[g] = mnew;
            float rsum = 0.0f;
#pragma unroll
            for (int j = 0; j < 4; j++)
#pragma unroll
                for (int r = 0; r < 4; r++) {
                    float p = exp2_fast(sv[j][r] - mnew);
                    sv[j][r] = p;
                    rsum += p;
                }
            rsum += __shfl_xor(rsum, 16);
            rsum += __shfl_xor(rsum, 32);
            l_st[g] = l_st[g] * alpha + rsum;
#pragma unroll
            for (int n = 0; n < 4; n++)
#pragma unroll
                for (int r = 0; r < 4; r++) o[g][n][r] *= alpha;
            // P -> LDS (8B row-contiguous packs), read back as B-frag
            u16* P = &Ps[wave * 32 * LS + g * 16 * LS];
#pragma unroll
            for (int j = 0; j < 4; j++) {
                ushort4 w;
                w.x = f2bf(sv[j][0]); w.y = f2bf(sv[j][1]);
                w.z = f2bf(sv[j][2]); w.w = f2bf(sv[j][3]);
                *(ushort4*)&P[l15 * LS + j * 16 + quad * 4] = w;
            }
            pf[g][0] = *(const bf16x8*)&P[l15 * LS + quad * 8];
            pf[g][1] = *(const bf16x8*)&P[l15 * LS + 32 + quad * 8];
        }
        // ---- O^T += V^T P^T : V frags read ONCE, used by both groups ----
#pragma unroll
        for (int n = 0; n < 4; n++) {
            const int vrow = n * 16 + l15;
            bf16x8 vf0 = *(const bf16x8*)&Vs[vrow * LS + quad * 8];
            bf16x8 vf1 = *(const bf16x8*)&Vs[vrow * LS + 32 + quad * 8];
#pragma unroll
            for (int g = 0; g < 2; g++) {
                o[g][n] = MFMA(vf0, pf[g][0], o[g][n]);
                o[g][n] = MFMA(vf1, pf[g][1], o[g][n]);
            }
        }
    }

    // partial epilogue per group: On = O/l (bf16) -> PO[seg]; (m,l) -> ML[seg]
#pragma unroll
    for (int g = 0; g < 2; g++) {
        const float iv = (l_st[g] > 0.0f) ? 1.0f / l_st[g] : 0.0f;
        u16* pp = &PO[(size_t)seg * 4194304 +
                      (size_t)((b_ * 4096 + base_r + g * 16 + l15) * 8 + h) * 64];
#pragma unroll
        for (int n = 0; n < 4; n++) {
            ushort4 w;
            w.x = f2bf(o[g][n][0] * iv);
            w.y = f2bf(o[g][n][1] * iv);
            w.z = f2bf(o[g][n][2] * iv);
            w.w = f2bf(o[g][n][3] * iv);
            *(ushort4*)&pp[n * 16 + quad * 4] = w;
        }
        if (quad == 0) {
            float* mlp = &ML[((seg * 16 + bh) * 4096 + base_r + g * 16 + l15) * 2];
            mlp[0] = m_st[g];
            mlp[1] = l_st[g];
        }
    }
}

// ---------------------------------------------------------------------------
// Merge: Y = (w0*On0 + w1*On1)/(w0+w1), wi = exp2(mi-m)*li -> qy_ws (bf16)
// ---------------------------------------------------------------------------
__global__ __launch_bounds__(256) void merge_k(
    const u16* __restrict__ PO, const float* __restrict__ ML, u16* __restrict__ Y)
{
    const int flat = blockIdx.x * 256 + threadIdx.x;
    const int rs = flat >> 6;
    const int rem = flat & 63;
    const int h = rem >> 3, c = rem & 7;
    const int b_ = rs >> 12, s = rs & 4095;
    const int bh = b_ * 8 + h;
    const float m0 = ML[(bh * 4096 + s) * 2];
    const float l0 = ML[(bh * 4096 + s) * 2 + 1];
    const float m1 = ML[((16 + bh) * 4096 + s) * 2];
    const float l1 = ML[((16 + bh) * 4096 + s) * 2 + 1];
    const float m = fmaxf(m0, m1);
    const float w0 = (l0 > 0.0f) ? exp2_fast(m0 - m) * l0 : 0.0f;
    const float w1 = (l1 > 0.0f) ? exp2_fast(m1 - m) * l1 : 0.0f;
    const float inv = 1.0f / (w0 + w1);
    const float a0 = w0 * inv, a1 = w1 * inv;

    const size_t base = (size_t)(rs * 8 + h) * 64 + c * 8;
    bf16x8 x0 = *(const bf16x8*)&PO[base];
    bf16x8 x1 = *(const bf16x8*)&PO[4194304 + base];
    ushort4 lo, hi;
    lo.x = f2bf(a0 * (float)x0[0] + a1 * (float)x1[0]);
    lo.y = f2bf(a0 * (float)x0[1] + a1 * (float)x1[1]);
    lo.z = f2bf(a0 * (float)x0[2] + a1 * (float)x1[2]);
    lo.w = f2bf(a0 * (float)x0[3] + a1 * (float)x1[3]);
    hi.x = f2bf(a0 * (float)x0[4] + a1 * (float)x1[4]);
    hi.y = f2bf(a0 * (float)x0[5] + a1 * (float)x1[5]);
    hi.z = f2bf(a0 * (float)x0[6] + a1 * (float)x1[6]);
    hi.w = f2bf(a0 * (float)x0[7] + a1 * (float)x1[7]);
    *(ushort4*)&Y[base] = lo;
    *(ushort4*)&Y[base + 4] = hi;
}

// ---------------------------------------------------------------------------
// GEMM3: out = y @ Wo^T + bo. A bf16 ws via global_load_lds; W fp32 native-cvt.
// ---------------------------------------------------------------------------
__global__ __launch_bounds__(256) void gemm_o_k(
    const u16* __restrict__ X, const float* __restrict__ W,
    const float* __restrict__ bias, float* __restrict__ Out)
{
    __shared__ u16 As[128 * 32];
    __shared__ u16 Bs[128 * 32];
    const int K = 512;
    const int tid = threadIdx.x, wave = tid >> 6, lane = tid & 63;
    const int l15 = lane & 15, quad = lane >> 4;
    const int bm = blockIdx.x * 128, bn = blockIdx.y * 128;
    const int wr = wave >> 1, wc = wave & 1;
    const int arow = lane >> 2;
    const int acol = (lane & 3) * 8;
    const int srow = tid >> 1;
    const int sc0 = (tid & 1) * 16;

    f32x4 acc[4][4] = {};
    for (int k0 = 0; k0 < K; k0 += 32) {
        __syncthreads();
#pragma unroll
        for (int ii = 0; ii < 2; ii++) {
            const int inst = wave * 2 + ii;
            const int row = inst * 16 + arow;
            load_lds16(&X[(bm + row) * K + k0 + acol], &As[inst * 512]);
        }
#pragma unroll
        for (int j = 0; j < 4; j++) {
            float4 wv = *(const float4*)&W[(bn + srow) * K + k0 + sc0 + j * 4];
            *(ushort4*)&Bs[srow * 32 + sc0 + j * 4] = f4_to_bf4(wv);
        }
        __syncthreads();
        bf16x8 a[4], b[4];
#pragma unroll
        for (int i = 0; i < 4; i++)
            a[i] = *(const bf16x8*)&As[(wr * 64 + i * 16 + l15) * 32 + quad * 8];
#pragma unroll
        for (int j = 0; j < 4; j++)
            b[j] = *(const bf16x8*)&Bs[(wc * 64 + j * 16 + l15) * 32 + quad * 8];
#pragma unroll
        for (int i = 0; i < 4; i++)
#pragma unroll
            for (int j = 0; j < 4; j++)
                acc[i][j] = MFMA(a[i], b[j], acc[i][j]);
    }
#pragma unroll
    for (int j = 0; j < 4; j++) {
        const int n_g = bn + wc * 64 + j * 16 + l15;
        const float bv = bias[n_g];
#pragma unroll
        for (int i = 0; i < 4; i++) {
            const int m0 = bm + wr * 64 + i * 16 + quad * 4;
#pragma unroll
            for (int r = 0; r < 4; r++)
                Out[(m0 + r) * 512 + n_g] = acc[i][j][r] + bv;
        }
    }
}

extern "C" void kernel_launch(void* const* d_in, const int* in_sizes, int n_in,
                              void* d_out, int out_size, void* d_ws, size_t ws_size,
                              hipStream_t stream) {
    (void)in_sizes; (void)n_in; (void)out_size; (void)ws_size;
    const float* x    = (const float*)d_in[0];
    const float* Wqkv = (const float*)d_in[1];
    const float* bqkv = (const float*)d_in[2];
    const float* Wo   = (const float*)d_in[3];
    const float* bo   = (const float*)d_in[4];
    float* out = (float*)d_out;

    u16* qy_ws = (u16*)d_ws;                 // 8 MiB  [b][s][h][hd] (Q, then Y)
    u16* k_ws  = qy_ws + 4194304;            // 8 MiB  [bh][s][64]
    u16* vt_ws = k_ws + 4194304;             // 8 MiB  [bh][64][s]
    float* ml  = (float*)(vt_ws + 4194304);  // 1 MiB  [2][16][4096][2] f32
    u16* po    = (u16*)d_out;                // 16 MiB partial O (dead until gemm3)

    gemm_qkv_k<<<dim3(64, 12), 256, 0, stream>>>(x, Wqkv, bqkv, qy_ws, k_ws, vt_ws);
    attn_k<<<dim3(64, 16), 256, 0, stream>>>(qy_ws, k_ws, vt_ws, po, ml);
    merge_k<<<2048, 256, 0, stream>>>(po, ml, qy_ws);
    gemm_o_k<<<dim3(64, 4), 256, 0, stream>>>(qy_ws, Wo, bo, out);
}

// Round 10
// 225.332 us; speedup vs baseline: 1.3778x; 1.3778x over previous
//
#include <hip/hip_runtime.h>

// B=2, S=4096, D=512, H=8, HD=64. fp32 in/out; bf16 MFMA internally.
// ws (27 MiB): qy[2][4096][8][64] (Q, then Y) | K[16][4096][64] | V^T[16][64][4096]
//              | ml[2][16][4096][2] f32 | wqkvb[1536*512] bf16 | wob[512*512] bf16
// d_out (16 MiB): xb bf16 scratch (until gemm1 done), then PO[2][...] partials.

typedef __bf16 bf16x8 __attribute__((ext_vector_type(8)));
typedef float f32x4 __attribute__((ext_vector_type(4)));
typedef unsigned short u16;

#define MFMA(a, b, c) __builtin_amdgcn_mfma_f32_16x16x32_bf16(a, b, c, 0, 0, 0)
#define QSCALE 0.18033688011112042f   // 1/sqrt(64) * log2(e)

__device__ __forceinline__ float exp2_fast(float x) {
    return __builtin_amdgcn_exp2f(x);
}
__device__ __forceinline__ u16 f2bf(float f) {
    union { __bf16 h; u16 u; } v; v.h = (__bf16)f; return v.u;
}
__device__ __forceinline__ ushort4 f4_to_bf4(float4 v) {
    ushort4 r;
    r.x = f2bf(v.x); r.y = f2bf(v.y); r.z = f2bf(v.z); r.w = f2bf(v.w);
    return r;
}
__device__ __forceinline__ void load_lds16(const u16* g, u16* l) {
    __builtin_amdgcn_global_load_lds(
        (const __attribute__((address_space(1))) void*)g,
        (__attribute__((address_space(3))) void*)l, 16, 0, 0);
}

// ---------------------------------------------------------------------------
// One fused fp32->bf16 convert for x, Wqkv, Wo (memory-bound, ~24MB traffic)
// ---------------------------------------------------------------------------
__global__ __launch_bounds__(256) void cvt_all(
    const float* __restrict__ x, const float* __restrict__ wq,
    const float* __restrict__ wo,
    u16* __restrict__ xb, u16* __restrict__ wqb, u16* __restrict__ wob)
{
    int i = blockIdx.x * 256 + threadIdx.x;
    if (i < 1048576) {
        ((ushort4*)xb)[i] = f4_to_bf4(((const float4*)x)[i]);
    } else if (i < 1048576 + 196608) {
        int j = i - 1048576;
        ((ushort4*)wqb)[j] = f4_to_bf4(((const float4*)wq)[j]);
    } else {
        int j = i - 1048576 - 196608;
        ((ushort4*)wob)[j] = f4_to_bf4(((const float4*)wo)[j]);
    }
}

// ---------------------------------------------------------------------------
// GEMM1 (all bf16, pure global_load_lds): qkv = x @ Wqkv^T + b
//   Q(scaled) -> qy[b][s][h][hd];  K -> [bh][s][64];  V^T -> [bh][64][s]
// ---------------------------------------------------------------------------
__global__ __launch_bounds__(256) void gemm_qkv_bf(
    const u16* __restrict__ X, const u16* __restrict__ W,
    const float* __restrict__ bias,
    u16* __restrict__ QY, u16* __restrict__ Ko, u16* __restrict__ Vto)
{
    __shared__ u16 As[128 * 32];
    __shared__ u16 Bs[128 * 32];
    const int K = 512;
    const int tid = threadIdx.x, wave = tid >> 6, lane = tid & 63;
    const int l15 = lane & 15, quad = lane >> 4;
    const int bm = blockIdx.x * 128, bn = blockIdx.y * 128;
    const int wr = wave >> 1, wc = wave & 1;
    const int arow = lane >> 2;
    const int acol = (lane & 3) * 8;

    f32x4 acc[4][4] = {};
    for (int k0 = 0; k0 < K; k0 += 32) {
        __syncthreads();
#pragma unroll
        for (int ii = 0; ii < 2; ii++) {
            const int inst = wave * 2 + ii;
            const int row = inst * 16 + arow;
            load_lds16(&X[(bm + row) * K + k0 + acol], &As[inst * 512]);
            load_lds16(&W[(bn + row) * K + k0 + acol], &Bs[inst * 512]);
        }
        __syncthreads();
        bf16x8 a[4], b[4];
#pragma unroll
        for (int i = 0; i < 4; i++)
            a[i] = *(const bf16x8*)&As[(wr * 64 + i * 16 + l15) * 32 + quad * 8];
#pragma unroll
        for (int j = 0; j < 4; j++)
            b[j] = *(const bf16x8*)&Bs[(wc * 64 + j * 16 + l15) * 32 + quad * 8];
#pragma unroll
        for (int i = 0; i < 4; i++)
#pragma unroll
            for (int j = 0; j < 4; j++)
                acc[i][j] = MFMA(a[i], b[j], acc[i][j]);
    }

    const int nbase = bn + wc * 64;
    const int which = nbase >> 9;  // 0=q 1=k 2=v
#pragma unroll
    for (int j = 0; j < 4; j++) {
        const int n_g = nbase + j * 16 + l15;
        const float bv = bias[n_g];
        const int d = n_g & 511, h = d >> 6, hd = d & 63;
#pragma unroll
        for (int i = 0; i < 4; i++) {
            const int m0 = bm + wr * 64 + i * 16 + quad * 4;
            const int b_ = m0 >> 12, s0 = m0 & 4095;
            if (which == 2) {
                ushort4 pk;
                pk.x = f2bf(acc[i][j][0] + bv);
                pk.y = f2bf(acc[i][j][1] + bv);
                pk.z = f2bf(acc[i][j][2] + bv);
                pk.w = f2bf(acc[i][j][3] + bv);
                *(ushort4*)&Vto[((b_ * 8 + h) * 64 + hd) * 4096 + s0] = pk;
            } else if (which == 1) {
#pragma unroll
                for (int r = 0; r < 4; r++)
                    Ko[((b_ * 8 + h) * 4096 + s0 + r) * 64 + hd] = f2bf(acc[i][j][r] + bv);
            } else {
#pragma unroll
                for (int r = 0; r < 4; r++)
                    QY[((b_ * 4096 + s0 + r) * 8 + h) * 64 + hd] =
                        f2bf((acc[i][j][r] + bv) * QSCALE);
            }
        }
    }
}

// ---------------------------------------------------------------------------
// Split-K flash attention (r8-exact). Block = 64 q-rows, 4 waves x 16.
// blockIdx.x in [0,128): qt = 63-(x>>1) (heavy first), seg = x&1.
// ---------------------------------------------------------------------------
#define LS 72

__global__ __launch_bounds__(256, 4) void attn_k(
    const u16* __restrict__ QY, const u16* __restrict__ Kk, const u16* __restrict__ Vt,
    u16* __restrict__ PO, float* __restrict__ ML)
{
    __shared__ u16 Ks[64 * LS];
    __shared__ u16 Vs[64 * LS];
    __shared__ u16 Ps[4 * 16 * LS];

    const int tid = threadIdx.x, wave = tid >> 6, lane = tid & 63;
    const int l15 = lane & 15, quad = lane >> 4;
    const int bh = blockIdx.y;
    const int b_ = bh >> 3, h = bh & 7;
    const int xi = (int)blockIdx.x;
    const int qt = 63 - (xi >> 1);
    const int seg = xi & 1;
    const int total = qt + 1;
    const int half = (total + 1) >> 1;
    const int kt0 = seg ? half : 0;
    const int kt1 = seg ? total : half;
    const int base_r = qt * 64 + wave * 16;

    const u16* qp = &QY[((b_ * 4096 + base_r + l15) * 8 + h) * 64];
    bf16x8 qf0 = *(const bf16x8*)&qp[quad * 8];
    bf16x8 qf1 = *(const bf16x8*)&qp[32 + quad * 8];

    f32x4 o[4] = {};
    float m_st = -1e30f, l_st = 0.0f;

    const int srow = tid >> 2;
    const int scol = (tid & 3) * 16;
    const u16* Kg = &Kk[(bh * 4096 + srow) * 64 + scol];
    const u16* Vg = &Vt[(bh * 64 + srow) * 4096 + scol];

    bf16x8 pk0, pk1, pv0, pv1;
    if (kt0 < kt1) {
        pk0 = *(const bf16x8*)&Kg[kt0 * 4096];
        pk1 = *(const bf16x8*)&Kg[kt0 * 4096 + 8];
        pv0 = *(const bf16x8*)&Vg[kt0 * 64];
        pv1 = *(const bf16x8*)&Vg[kt0 * 64 + 8];
    }

    for (int kt = kt0; kt < kt1; kt++) {
        const int k0 = kt * 64;
        __syncthreads();
        *(bf16x8*)&Ks[srow * LS + scol] = pk0;
        *(bf16x8*)&Ks[srow * LS + scol + 8] = pk1;
        *(bf16x8*)&Vs[srow * LS + scol] = pv0;
        *(bf16x8*)&Vs[srow * LS + scol + 8] = pv1;
        if (kt + 1 < kt1) {
            pk0 = *(const bf16x8*)&Kg[(kt + 1) * 4096];
            pk1 = *(const bf16x8*)&Kg[(kt + 1) * 4096 + 8];
            pv0 = *(const bf16x8*)&Vg[(kt + 1) * 64];
            pv1 = *(const bf16x8*)&Vg[(kt + 1) * 64 + 8];
        }
        __syncthreads();

        f32x4 sc[4];
#pragma unroll
        for (int j = 0; j < 4; j++) {
            const int krow = j * 16 + l15;
            bf16x8 kf0 = *(const bf16x8*)&Ks[krow * LS + quad * 8];
            bf16x8 kf1 = *(const bf16x8*)&Ks[krow * LS + 32 + quad * 8];
            f32x4 s = {};
            s = MFMA(kf0, qf0, s);
            s = MFMA(kf1, qf1, s);
            sc[j] = s;
        }
        const bool needmask = (k0 + 63 > base_r);
        float sv[4][4];
#pragma unroll
        for (int j = 0; j < 4; j++)
#pragma unroll
            for (int r = 0; r < 4; r++) {
                float v = sc[j][r];
                if (needmask) {
                    const int key = k0 + j * 16 + quad * 4 + r;
                    if (key > base_r + l15) v = -1e30f;
                }
                sv[j][r] = v;
            }
        float rmax = sv[0][0];
#pragma unroll
        for (int j = 0; j < 4; j++)
#pragma unroll
            for (int r = 0; r < 4; r++) rmax = fmaxf(rmax, sv[j][r]);
        rmax = fmaxf(rmax, __shfl_xor(rmax, 16));
        rmax = fmaxf(rmax, __shfl_xor(rmax, 32));
        const float mnew = fmaxf(m_st, rmax);
        const float alpha = exp2_fast(m_st - mnew);
        m_st = mnew;
        float rsum = 0.0f;
#pragma unroll
        for (int j = 0; j < 4; j++)
#pragma unroll
            for (int r = 0; r < 4; r++) {
                float p = exp2_fast(sv[j][r] - mnew);
                sv[j][r] = p;
                rsum += p;
            }
        rsum += __shfl_xor(rsum, 16);
        rsum += __shfl_xor(rsum, 32);
        l_st = l_st * alpha + rsum;
#pragma unroll
        for (int n = 0; n < 4; n++)
#pragma unroll
            for (int r = 0; r < 4; r++) o[n][r] *= alpha;
        u16* P = &Ps[wave * 16 * LS];
#pragma unroll
        for (int j = 0; j < 4; j++) {
            ushort4 w;
            w.x = f2bf(sv[j][0]); w.y = f2bf(sv[j][1]);
            w.z = f2bf(sv[j][2]); w.w = f2bf(sv[j][3]);
            *(ushort4*)&P[l15 * LS + j * 16 + quad * 4] = w;
        }
        bf16x8 pf0 = *(const bf16x8*)&P[l15 * LS + quad * 8];
        bf16x8 pf1 = *(const bf16x8*)&P[l15 * LS + 32 + quad * 8];
#pragma unroll
        for (int n = 0; n < 4; n++) {
            const int vrow = n * 16 + l15;
            bf16x8 vf0 = *(const bf16x8*)&Vs[vrow * LS + quad * 8];
            bf16x8 vf1 = *(const bf16x8*)&Vs[vrow * LS + 32 + quad * 8];
            o[n] = MFMA(vf0, pf0, o[n]);
            o[n] = MFMA(vf1, pf1, o[n]);
        }
    }

    const float iv = (l_st > 0.0f) ? 1.0f / l_st : 0.0f;
    u16* pp = &PO[(size_t)seg * 4194304 +
                  (size_t)((b_ * 4096 + base_r + l15) * 8 + h) * 64];
#pragma unroll
    for (int n = 0; n < 4; n++) {
        ushort4 w;
        w.x = f2bf(o[n][0] * iv);
        w.y = f2bf(o[n][1] * iv);
        w.z = f2bf(o[n][2] * iv);
        w.w = f2bf(o[n][3] * iv);
        *(ushort4*)&pp[n * 16 + quad * 4] = w;
    }
    if (quad == 0) {
        float* mlp = &ML[((seg * 16 + bh) * 4096 + base_r + l15) * 2];
        mlp[0] = m_st;
        mlp[1] = l_st;
    }
}

// ---------------------------------------------------------------------------
// Merge (r8-exact): Y = (w0*On0 + w1*On1)/(w0+w1) -> qy_ws (bf16)
// ---------------------------------------------------------------------------
__global__ __launch_bounds__(256) void merge_k(
    const u16* __restrict__ PO, const float* __restrict__ ML, u16* __restrict__ Y)
{
    const int flat = blockIdx.x * 256 + threadIdx.x;
    const int rs = flat >> 6;
    const int rem = flat & 63;
    const int h = rem >> 3, c = rem & 7;
    const int b_ = rs >> 12, s = rs & 4095;
    const int bh = b_ * 8 + h;
    const float m0 = ML[(bh * 4096 + s) * 2];
    const float l0 = ML[(bh * 4096 + s) * 2 + 1];
    const float m1 = ML[((16 + bh) * 4096 + s) * 2];
    const float l1 = ML[((16 + bh) * 4096 + s) * 2 + 1];
    const float m = fmaxf(m0, m1);
    const float w0 = (l0 > 0.0f) ? exp2_fast(m0 - m) * l0 : 0.0f;
    const float w1 = (l1 > 0.0f) ? exp2_fast(m1 - m) * l1 : 0.0f;
    const float inv = 1.0f / (w0 + w1);
    const float a0 = w0 * inv, a1 = w1 * inv;

    const size_t base = (size_t)(rs * 8 + h) * 64 + c * 8;
    bf16x8 x0 = *(const bf16x8*)&PO[base];
    bf16x8 x1 = *(const bf16x8*)&PO[4194304 + base];
    ushort4 lo, hi;
    lo.x = f2bf(a0 * (float)x0[0] + a1 * (float)x1[0]);
    lo.y = f2bf(a0 * (float)x0[1] + a1 * (float)x1[1]);
    lo.z = f2bf(a0 * (float)x0[2] + a1 * (float)x1[2]);
    lo.w = f2bf(a0 * (float)x0[3] + a1 * (float)x1[3]);
    hi.x = f2bf(a0 * (float)x0[4] + a1 * (float)x1[4]);
    hi.y = f2bf(a0 * (float)x0[5] + a1 * (float)x1[5]);
    hi.z = f2bf(a0 * (float)x0[6] + a1 * (float)x1[6]);
    hi.w = f2bf(a0 * (float)x0[7] + a1 * (float)x1[7]);
    *(ushort4*)&Y[base] = lo;
    *(ushort4*)&Y[base + 4] = hi;
}

// ---------------------------------------------------------------------------
// GEMM3 (all bf16 in, pure global_load_lds): out = y @ Wo^T + bo, fp32 out
// ---------------------------------------------------------------------------
__global__ __launch_bounds__(256) void gemm_o_bf(
    const u16* __restrict__ X, const u16* __restrict__ W,
    const float* __restrict__ bias, float* __restrict__ Out)
{
    __shared__ u16 As[128 * 32];
    __shared__ u16 Bs[128 * 32];
    const int K = 512;
    const int tid = threadIdx.x, wave = tid >> 6, lane = tid & 63;
    const int l15 = lane & 15, quad = lane >> 4;
    const int bm = blockIdx.x * 128, bn = blockIdx.y * 128;
    const int wr = wave >> 1, wc = wave & 1;
    const int arow = lane >> 2;
    const int acol = (lane & 3) * 8;

    f32x4 acc[4][4] = {};
    for (int k0 = 0; k0 < K; k0 += 32) {
        __syncthreads();
#pragma unroll
        for (int ii = 0; ii < 2; ii++) {
            const int inst = wave * 2 + ii;
            const int row = inst * 16 + arow;
            load_lds16(&X[(bm + row) * K + k0 + acol], &As[inst * 512]);
            load_lds16(&W[(bn + row) * K + k0 + acol], &Bs[inst * 512]);
        }
        __syncthreads();
        bf16x8 a[4], b[4];
#pragma unroll
        for (int i = 0; i < 4; i++)
            a[i] = *(const bf16x8*)&As[(wr * 64 + i * 16 + l15) * 32 + quad * 8];
#pragma unroll
        for (int j = 0; j < 4; j++)
            b[j] = *(const bf16x8*)&Bs[(wc * 64 + j * 16 + l15) * 32 + quad * 8];
#pragma unroll
        for (int i = 0; i < 4; i++)
#pragma unroll
            for (int j = 0; j < 4; j++)
                acc[i][j] = MFMA(a[i], b[j], acc[i][j]);
    }
#pragma unroll
    for (int j = 0; j < 4; j++) {
        const int n_g = bn + wc * 64 + j * 16 + l15;
        const float bv = bias[n_g];
#pragma unroll
        for (int i = 0; i < 4; i++) {
            const int m0 = bm + wr * 64 + i * 16 + quad * 4;
#pragma unroll
            for (int r = 0; r < 4; r++)
                Out[(m0 + r) * 512 + n_g] = acc[i][j][r] + bv;
        }
    }
}

extern "C" void kernel_launch(void* const* d_in, const int* in_sizes, int n_in,
                              void* d_out, int out_size, void* d_ws, size_t ws_size,
                              hipStream_t stream) {
    (void)in_sizes; (void)n_in; (void)out_size; (void)ws_size;
    const float* x    = (const float*)d_in[0];
    const float* Wqkv = (const float*)d_in[1];
    const float* bqkv = (const float*)d_in[2];
    const float* Wo   = (const float*)d_in[3];
    const float* bo   = (const float*)d_in[4];
    float* out = (float*)d_out;

    u16* qy_ws = (u16*)d_ws;                 // 8 MiB  [b][s][h][hd] (Q, then Y)
    u16* k_ws  = qy_ws + 4194304;            // 8 MiB  [bh][s][64]
    u16* vt_ws = k_ws + 4194304;             // 8 MiB  [bh][64][s]
    float* ml  = (float*)(vt_ws + 4194304);  // 1 MiB  [2][16][4096][2] f32
    u16* wqkvb = (u16*)(ml + 262144);        // 1.5 MiB bf16 Wqkv
    u16* wob   = wqkvb + 786432;             // 0.5 MiB bf16 Wo    (27 MiB total)
    u16* xb    = (u16*)d_out;                // 8 MiB bf16 x (dead before attn)
    u16* po    = (u16*)d_out;                // 16 MiB partials (after gemm1)

    cvt_all<<<5120, 256, 0, stream>>>(x, Wqkv, Wo, xb, wqkvb, wob);
    gemm_qkv_bf<<<dim3(64, 12), 256, 0, stream>>>(xb, wqkvb, bqkv, qy_ws, k_ws, vt_ws);
    attn_k<<<dim3(128, 16), 256, 0, stream>>>(qy_ws, k_ws, vt_ws, po, ml);
    merge_k<<<2048, 256, 0, stream>>>(po, ml, qy_ws);
    gemm_o_bf<<<dim3(64, 4), 256, 0, stream>>>(qy_ws, wob, bo, out);
}